// Round 1
// baseline (23147.180 us; speedup 1.0000x reference)
//
#include <hip/hip_runtime.h>
#include <hip/hip_bf16.h>

// trajectory2seq: 2-layer Elman RNN encoder (SEQ=256) + greedy decoder (32 steps)
// Strategy:
//  - encoder ih-parts hoisted into two big fp32 GEMMs (k_gemm)
//  - persistent scan kernels for the hh-recurrence (weights in VGPRs, flag barriers)
//  - decoder: one persistent kernel; cell in fp32 (LDS-resident weights),
//    logits via bf16 MFMA (16x16x32) + exact-fp32 argmax refinement (margin 0.05)
// All recurrence math fp32 (argmax feedback is chaos-sensitive; bf16 in h would flip tokens).

typedef float v4f __attribute__((ext_vector_type(4)));
typedef short short8 __attribute__((ext_vector_type(8)));

#define HID 512
#define NBAT 64
#define SEQL 256
#define NV 32000
#define TDEC 32
#define BH (64 * 512)

__device__ __forceinline__ unsigned short f2bf(float f) {
  unsigned u = __float_as_uint(f);
  u = u + 0x7FFFu + ((u >> 16) & 1u);  // RNE
  return (unsigned short)(u >> 16);
}
// monotonic float->uint encoding for atomicMax-based argmax
__device__ __forceinline__ unsigned fenc(float f) {
  unsigned u = __float_as_uint(f);
  return (u & 0x80000000u) ? ~u : (u | 0x80000000u);
}

// flag barrier: each wg publishes its epoch; threads [0,count) poll group's flags.
__device__ __forceinline__ void wgbar(int* flags, int wg, int first, int count, unsigned ep) {
  __syncthreads();
  if (threadIdx.x == 0) {
    __threadfence();
    __hip_atomic_store(&flags[wg], (int)ep, __ATOMIC_RELEASE, __HIP_MEMORY_SCOPE_AGENT);
  }
  if ((int)threadIdx.x < count) {
    const int* f = &flags[first + (int)threadIdx.x];
    while ((unsigned)__hip_atomic_load(f, __ATOMIC_ACQUIRE, __HIP_MEMORY_SCOPE_AGENT) < ep)
      __builtin_amdgcn_s_sleep(1);
  }
  __syncthreads();
  __threadfence();
}

// ---------------- W_fc fp32 -> bf16 ----------------
__global__ void k_wfcb(const float* __restrict__ W, unsigned short* __restrict__ Wb) {
  const int n = NV * HID;
  for (int i = ((int)blockIdx.x * 256 + (int)threadIdx.x) * 8; i < n; i += 2048 * 256 * 8) {
    v4f a = *(const v4f*)(W + i);
    v4f b = *(const v4f*)(W + i + 4);
    short8 o;
    o[0] = (short)f2bf(a[0]); o[1] = (short)f2bf(a[1]);
    o[2] = (short)f2bf(a[2]); o[3] = (short)f2bf(a[3]);
    o[4] = (short)f2bf(b[0]); o[5] = (short)f2bf(b[1]);
    o[6] = (short)f2bf(b[2]); o[7] = (short)f2bf(b[3]);
    *(short8*)(Wb + i) = o;
  }
}

// ---------------- fp32 GEMM: P[i][j] = sum_k A[i][k]*W[j][k] + bias[j] ----------------
// A rows i = t*64+b; GATHER: A[i][k] = emb[x[b][t]][k]. Tile 128x128, micro 8x8, kc=32.
template <int GATHER>
__global__ __launch_bounds__(256, 2) void k_gemm(const float* __restrict__ A,
                                                 const int* __restrict__ xtok,
                                                 const float* __restrict__ emb,
                                                 const float* __restrict__ W,
                                                 const float* __restrict__ bias,
                                                 float* __restrict__ P) {
  __shared__ float As[32 * 132];
  __shared__ float Bs[32 * 132];
  const int tid = threadIdx.x;
  const int i0 = ((int)blockIdx.x >> 2) * 128, j0 = ((int)blockIdx.x & 3) * 128;
  const int tx = tid & 15, ty = tid >> 4;
  float acc[8][8] = {};
  const int sa = 4 * ((tx >> 2) & 1);
  const int sb = 4 * ((ty >> 2) & 1);
  const int pa0 = (tx * 8) ^ sa, pa1 = (tx * 8 + 4) ^ sa;  // xor-swizzle => 2-way banks (free)
  const int pb0 = (ty * 8) ^ sb, pb1 = (ty * 8 + 4) ^ sb;
  for (int kc = 0; kc < HID; kc += 32) {
#pragma unroll
    for (int u = 0; u < 4; u++) {
      int lin = tid + u * 256;
      int il = lin >> 3, kq = (lin & 7) * 4;
      int pi = il ^ (4 * ((il >> 5) & 1));
      const float* asrc;
      if (GATHER) {
        int row = i0 + il;
        int tok = xtok[(row & 63) * SEQL + (row >> 6)];  // x[b][t], row = t*64+b
        asrc = emb + (size_t)tok * HID + kc + kq;
      } else {
        asrc = A + (size_t)(i0 + il) * HID + kc + kq;
      }
      v4f av = *(const v4f*)asrc;
      v4f bv = *(const v4f*)(W + (size_t)(j0 + il) * HID + kc + kq);
      As[(kq + 0) * 132 + pi] = av[0]; As[(kq + 1) * 132 + pi] = av[1];
      As[(kq + 2) * 132 + pi] = av[2]; As[(kq + 3) * 132 + pi] = av[3];
      Bs[(kq + 0) * 132 + pi] = bv[0]; Bs[(kq + 1) * 132 + pi] = bv[1];
      Bs[(kq + 2) * 132 + pi] = bv[2]; Bs[(kq + 3) * 132 + pi] = bv[3];
    }
    __syncthreads();
#pragma unroll 8
    for (int k = 0; k < 32; k++) {
      v4f a0 = *(const v4f*)&As[k * 132 + pa0];
      v4f a1 = *(const v4f*)&As[k * 132 + pa1];
      v4f b0 = *(const v4f*)&Bs[k * 132 + pb0];
      v4f b1 = *(const v4f*)&Bs[k * 132 + pb1];
      float ar[8] = {a0[0], a0[1], a0[2], a0[3], a1[0], a1[1], a1[2], a1[3]};
      float br[8] = {b0[0], b0[1], b0[2], b0[3], b1[0], b1[1], b1[2], b1[3]};
#pragma unroll
      for (int r = 0; r < 8; r++)
#pragma unroll
        for (int c = 0; c < 8; c++) acc[r][c] = fmaf(ar[r], br[c], acc[r][c]);
    }
    __syncthreads();
  }
  v4f bl0 = *(const v4f*)(bias + j0 + ty * 8);
  v4f bl1 = *(const v4f*)(bias + j0 + ty * 8 + 4);
#pragma unroll
  for (int r = 0; r < 8; r++) {
    float* dst = P + (size_t)(i0 + tx * 8 + r) * HID + j0 + ty * 8;
    v4f o0 = {acc[r][0] + bl0[0], acc[r][1] + bl0[1], acc[r][2] + bl0[2], acc[r][3] + bl0[3]};
    v4f o1 = {acc[r][4] + bl1[0], acc[r][5] + bl1[1], acc[r][6] + bl1[2], acc[r][7] + bl1[3]};
    *(v4f*)dst = o0;
    *(v4f*)(dst + 4) = o1;
  }
}

// ---------------- persistent recurrence scan ----------------
// 256 wgs = 8 batch-groups (8 batches) x 32 j-groups (16 neurons).
// h_t = tanh(P[t] + bhh + h_{t-1} @ Whh^T); Whh slice lives in VGPRs for all 256 steps.
// Barrier only among the 32 wgs of one batch-group (flag poll).
__global__ __launch_bounds__(256, 2) void k_scan(float* __restrict__ P,
                                                 const float* __restrict__ Whh,
                                                 const float* __restrict__ bhh,
                                                 float* __restrict__ hbuf,
                                                 int* __restrict__ flags, int store_h,
                                                 unsigned ep) {
  __shared__ float hs[32 * 132];  // stage [ks32][b8][k16] (+4 pad), aliased as partial buffer
  const int wg = blockIdx.x, tid = threadIdx.x;
  const int bg = wg >> 5, jg = wg & 31;
  const int b0 = bg * 8, j0 = jg * 16;
  const int bh = tid & 1, jg2 = (tid >> 1) & 3, ks = tid >> 3;  // thread: 4b x 4j x 16k
  v4f wv[4][4];
#pragma unroll
  for (int jj = 0; jj < 4; jj++)
#pragma unroll
    for (int i4 = 0; i4 < 4; i4++)
      wv[jj][i4] = *(const v4f*)(Whh + (size_t)(j0 + jg2 * 4 + jj) * HID + ks * 16 + i4 * 4);
  for (int t = 0; t < SEQL; t++) {
    const int p = t & 1;
    float* Pt = P + (size_t)t * BH;
    const float* hsrc = hbuf + p * BH + b0 * HID;
#pragma unroll
    for (int u = 0; u < 4; u++) {
      int lin = tid + u * 256;
      int b = lin >> 7, k4 = (lin & 127) * 4;
      *(v4f*)&hs[(k4 >> 4) * 132 + b * 16 + (k4 & 15)] = *(const v4f*)(hsrc + b * HID + k4);
    }
    __syncthreads();
    float acc[4][4] = {};
#pragma unroll
    for (int i4 = 0; i4 < 4; i4++) {
#pragma unroll
      for (int bb = 0; bb < 4; bb++) {
        int b = bh * 4 + bb;
        v4f hv = *(const v4f*)&hs[ks * 132 + b * 16 + i4 * 4];
#pragma unroll
        for (int jj = 0; jj < 4; jj++) {
          float a = acc[bb][jj];
          a = fmaf(hv[0], wv[jj][i4][0], a);
          a = fmaf(hv[1], wv[jj][i4][1], a);
          a = fmaf(hv[2], wv[jj][i4][2], a);
          a = fmaf(hv[3], wv[jj][i4][3], a);
          acc[bb][jj] = a;
        }
      }
    }
    __syncthreads();  // done reading hs -> alias as partials [ks][b8][j16]
#pragma unroll
    for (int bb = 0; bb < 4; bb++) {
      v4f pv = {acc[bb][0], acc[bb][1], acc[bb][2], acc[bb][3]};
      *(v4f*)&hs[ks * 132 + (bh * 4 + bb) * 16 + jg2 * 4] = pv;
    }
    __syncthreads();
    if (tid < 128) {
      int bb = tid >> 4, jj = tid & 15;
      float sum = 0.f;
#pragma unroll
      for (int k2 = 0; k2 < 32; k2++) sum += hs[k2 * 132 + bb * 16 + jj];
      int jglob = j0 + jj, bglob = b0 + bb;
      float z = Pt[bglob * HID + jglob] + bhh[jglob] + sum;
      float h = tanhf(z);
      hbuf[(p ^ 1) * BH + bglob * HID + jglob] = h;
      if (store_h) Pt[bglob * HID + jglob] = h;  // in-place H history for layer-1 GEMM
    }
    wgbar(flags, wg, bg * 32, 32, ++ep);
  }
}

// ---------------- persistent decoder ----------------
// 256 wgs. Cell roles: 4 batch-groups (16 b) x 64 j-groups (8 j); fc roles: wg<250 -> 128 cols;
// argmax roles: wg = b*4 + quarter. Per step: A(cell l0) -> bg-bar -> B(cell l1) -> full-bar ->
// C(bf16-MFMA logits + tile row-max) -> full-bar -> E(candidates>=max-0.05, exact fp32 refine,
// atomicMax 64-bit (value, smallest-index tie-break)) -> bg-bar -> next step decodes tokens.
__global__ __launch_bounds__(256, 1) void k_decoder(
    const float* __restrict__ emb, const float* __restrict__ Wih, const float* __restrict__ Whh,
    const float* __restrict__ bih, const float* __restrict__ bhh, const float* __restrict__ Wfc,
    const float* __restrict__ bfc, const unsigned short* __restrict__ Wfcb,
    float* __restrict__ h0buf, float* __restrict__ h1buf, unsigned short* __restrict__ h1bf,
    float* __restrict__ pmaxp, unsigned long long* __restrict__ best, int* __restrict__ flags,
    float* __restrict__ out, unsigned ep) {
  __shared__ float Wl[4 * 4224];  // [ih0,hh0,ih1,hh1][ks32][j8][k16]+pad
  __shared__ float es[32 * 268];  // ih-operand stage [ks][b16][k16]+pad; aliased: partials/pmr/red
  __shared__ float hss[32 * 268]; // hh-operand stage
  const int wg = blockIdx.x, tid = threadIdx.x;
  const int bg = wg >> 6, jgD = wg & 63;
  const int bh = tid & 3, jg2 = (tid >> 2) & 1, ks = tid >> 3;
  for (int m = 0; m < 4; m++) {
    const float* src = ((m & 1) ? Whh : Wih) + (size_t)(m >> 1) * HID * HID;
#pragma unroll
    for (int u = 0; u < 4; u++) {
      int lin = tid + u * 256;
      int j = lin >> 7, k4 = (lin & 127) * 4;
      v4f v = *(const v4f*)(src + (size_t)(jgD * 8 + j) * HID + k4);
      *(v4f*)&Wl[m * 4224 + (k4 >> 4) * 132 + j * 16 + (k4 & 15)] = v;
    }
  }
  for (int st = 0; st < TDEC; st++) {
    const int p = st & 1;
    // ---- phases A (l0) / B (l1) ----
    for (int ph = 0; ph < 2; ph++) {
      if (ph == 1 && wg == 0 && tid < 64) best[tid] = 0ull;  // reset before E writes
#pragma unroll
      for (int u = 0; u < 8; u++) {
        int lin = tid + u * 256;
        int b = lin >> 7, k4 = (lin & 127) * 4;
        const float* se;
        if (ph == 0) {
          unsigned vtok = 0u;
          if (st > 0) {
            unsigned long long kk = best[bg * 16 + b];
            vtok = 0xFFFFFFFFu - (unsigned)(kk & 0xFFFFFFFFull);
            if (vtok >= (unsigned)NV) vtok = 0u;
          }
          se = emb + (size_t)vtok * HID + k4;
        } else {
          se = h0buf + (p ^ 1) * BH + (bg * 16 + b) * HID + k4;
        }
        const float* sh = (ph == 0 ? h0buf : h1buf) + p * BH + (bg * 16 + b) * HID + k4;
        *(v4f*)&es[(k4 >> 4) * 268 + b * 16 + (k4 & 15)] = *(const v4f*)se;
        *(v4f*)&hss[(k4 >> 4) * 268 + b * 16 + (k4 & 15)] = *(const v4f*)sh;
      }
      __syncthreads();
      float acc[4][4] = {};
      const float* Wi = &Wl[(ph * 2 + 0) * 4224];
      const float* Wh = &Wl[(ph * 2 + 1) * 4224];
#pragma unroll
      for (int i4 = 0; i4 < 4; i4++) {
        v4f wi[4], wh[4];
#pragma unroll
        for (int jj = 0; jj < 4; jj++) {
          wi[jj] = *(const v4f*)&Wi[ks * 132 + (jg2 * 4 + jj) * 16 + i4 * 4];
          wh[jj] = *(const v4f*)&Wh[ks * 132 + (jg2 * 4 + jj) * 16 + i4 * 4];
        }
#pragma unroll
        for (int bb = 0; bb < 4; bb++) {
          int b = bh * 4 + bb;
          v4f evv = *(const v4f*)&es[ks * 268 + b * 16 + i4 * 4];
          v4f hvv = *(const v4f*)&hss[ks * 268 + b * 16 + i4 * 4];
#pragma unroll
          for (int jj = 0; jj < 4; jj++) {
            float a = acc[bb][jj];
            a = fmaf(evv[0], wi[jj][0], a); a = fmaf(evv[1], wi[jj][1], a);
            a = fmaf(evv[2], wi[jj][2], a); a = fmaf(evv[3], wi[jj][3], a);
            a = fmaf(hvv[0], wh[jj][0], a); a = fmaf(hvv[1], wh[jj][1], a);
            a = fmaf(hvv[2], wh[jj][2], a); a = fmaf(hvv[3], wh[jj][3], a);
            acc[bb][jj] = a;
          }
        }
      }
      __syncthreads();  // partials alias es: [ks32][b16][j8]+pad
#pragma unroll
      for (int bb = 0; bb < 4; bb++) {
        v4f pv = {acc[bb][0], acc[bb][1], acc[bb][2], acc[bb][3]};
        *(v4f*)&es[ks * 132 + (bh * 4 + bb) * 8 + jg2 * 4] = pv;
      }
      __syncthreads();
      if (tid < 128) {
        int b = tid >> 3, j = tid & 7;
        float sum = 0.f;
#pragma unroll
        for (int k2 = 0; k2 < 32; k2++) sum += es[k2 * 132 + b * 8 + j];
        int jglob = jgD * 8 + j, bglob = bg * 16 + b;
        float z = bih[ph * HID + jglob] + bhh[ph * HID + jglob] + sum;
        float h = tanhf(z);
        float* hb = (ph ? h1buf : h0buf);
        hb[(p ^ 1) * BH + bglob * HID + jglob] = h;
        if (ph) h1bf[bglob * HID + jglob] = f2bf(h);
      }
      if (ph == 0) wgbar(flags, wg, bg * 64, 64, ++ep);
      else         wgbar(flags, wg, 0, 256, ++ep);
    }
    // ---- phase C: logits = h1 @ Wfc^T + bfc, bf16 MFMA 16x16x32 ----
    if (wg < 250) {
      const int w = tid >> 6, lane = tid & 63;
      const int l16 = lane & 15, quad = lane >> 4;
      const int n0 = wg * 128 + w * 32;
      const int nc0 = n0 + l16, nc1 = n0 + 16 + l16;
      const float bf0 = bfc[nc0], bf1 = bfc[nc1];
      const int ko = quad * 8;
      v4f acc[4][2] = {};
#pragma unroll 4
      for (int kc = 0; kc < HID; kc += 32) {
        short8 b0 = *(const short8*)(Wfcb + (size_t)nc0 * HID + kc + ko);
        short8 b1 = *(const short8*)(Wfcb + (size_t)nc1 * HID + kc + ko);
#pragma unroll
        for (int mb = 0; mb < 4; mb++) {
          short8 a = *(const short8*)(h1bf + (size_t)(mb * 16 + l16) * HID + kc + ko);
          acc[mb][0] = __builtin_amdgcn_mfma_f32_16x16x32_bf16(a, b0, acc[mb][0], 0, 0, 0);
          acc[mb][1] = __builtin_amdgcn_mfma_f32_16x16x32_bf16(a, b1, acc[mb][1], 0, 0, 0);
        }
      }
      float* pmr = es;  // [4 waves][64 rows]
#pragma unroll
      for (int mb = 0; mb < 4; mb++) {
#pragma unroll
        for (int r = 0; r < 4; r++) {
          float v0 = acc[mb][0][r] + bf0;
          float v1 = acc[mb][1][r] + bf1;
          int m = mb * 16 + quad * 4 + r;  // C/D layout: col=lane&15, row=quad*4+reg
          out[(size_t)(m * TDEC + st) * NV + nc0] = v0;
          out[(size_t)(m * TDEC + st) * NV + nc1] = v1;
          float mx = fmaxf(v0, v1);
          mx = fmaxf(mx, __shfl_xor(mx, 1));
          mx = fmaxf(mx, __shfl_xor(mx, 2));
          mx = fmaxf(mx, __shfl_xor(mx, 4));
          mx = fmaxf(mx, __shfl_xor(mx, 8));
          if (l16 == 0) pmr[w * 64 + m] = mx;
        }
      }
      __syncthreads();
      if (tid < 64) {
        float m4 = fmaxf(fmaxf(pmr[tid], pmr[64 + tid]), fmaxf(pmr[128 + tid], pmr[192 + tid]));
        pmaxp[wg * 64 + tid] = m4;
      }
    }
    wgbar(flags, wg, 0, 256, ++ep);
    // ---- phase E: candidate refine + argmax ----
    {
      const int b = wg >> 2, q = wg & 3;
      float* red = es;
      red[tid] = (tid < 250) ? pmaxp[tid * 64 + b] : -3.0e38f;
      __syncthreads();
      for (int o = 128; o > 0; o >>= 1) {
        if (tid < o) red[tid] = fmaxf(red[tid], red[tid + o]);
        __syncthreads();
      }
      const float thr = red[0] - 0.05f;
      const float* hrow = h1buf + (p ^ 1) * BH + b * HID;
      const size_t ob = (size_t)(b * TDEC + st) * NV + q * 8000;
      for (int i = tid * 4; i < 8000; i += 1024) {
        v4f lv = *(const v4f*)(out + ob + i);
#pragma unroll
        for (int c = 0; c < 4; c++) {
          if (lv[c] >= thr) {
            int vidx = q * 8000 + i + c;
            const v4f* h4 = (const v4f*)hrow;
            const v4f* w4 = (const v4f*)(Wfc + (size_t)vidx * HID);
            v4f s0 = 0, s1 = 0;
            for (int k = 0; k < 128; k += 2) {
              s0 += h4[k] * w4[k];
              s1 += h4[k + 1] * w4[k + 1];
            }
            v4f sv = s0 + s1;
            float d = bfc[vidx] + sv[0] + sv[1] + sv[2] + sv[3];
            unsigned long long key =
                ((unsigned long long)fenc(d) << 32) |
                (unsigned long long)(0xFFFFFFFFu - (unsigned)vidx);  // ties -> smallest index
            atomicMax(&best[b], key);
          }
        }
      }
    }
    wgbar(flags, wg, bg * 64, 64, ++ep);
  }
  // h_fin: [2][64][512] appended after logits; final h is in slot 0 (s=31: p=1 -> wrote slot 0)
  int lin = wg * 256 + tid;
  int l = lin >> 15, r2 = lin & 32767;
  out[65536000 + lin] = (l ? h1buf : h0buf)[r2];
}

extern "C" void kernel_launch(void* const* d_in, const int* in_sizes, int n_in, void* d_out,
                              int out_size, void* d_ws, size_t ws_size, hipStream_t stream) {
  const int* x = (const int*)d_in[0];
  const float* emb = (const float*)d_in[1];
  const float* Wih = (const float*)d_in[2];
  const float* Whh = (const float*)d_in[3];
  const float* bih = (const float*)d_in[4];
  const float* bhh = (const float*)d_in[5];
  const float* Wfc = (const float*)d_in[6];
  const float* bfc = (const float*)d_in[7];
  float* out = (float*)d_out;
  char* ws = (char*)d_ws;

  // workspace map (needs ~100.6 MB)
  float* P0 = (float*)ws;                         // [256][64][512] -> becomes H0 in-place
  float* P1 = P0 + (size_t)SEQL * BH;             // [256][64][512]
  unsigned short* Wfcb = (unsigned short*)(P1 + (size_t)SEQL * BH);  // [32000][512] bf16
  char* small = (char*)(Wfcb + (size_t)NV * HID);
  float* h0buf = (float*)small;                   // [2][64][512]
  float* h1buf = h0buf + 2 * BH;                  // [2][64][512]
  unsigned short* h1bf = (unsigned short*)(h1buf + 2 * BH);  // [64][512] bf16
  float* pmaxp = (float*)(h1bf + BH);             // [256][64]
  unsigned long long* best = (unsigned long long*)(pmaxp + 256 * 64);  // [64]
  int* flags = (int*)(best + 64);                 // [256]
  size_t small_bytes = (size_t)2 * BH * 4 + (size_t)2 * BH * 4 + BH * 2 + 256 * 64 * 4 + 64 * 8 + 256 * 4;

  hipMemsetAsync(small, 0, small_bytes, stream);  // h init=0, best=0, flags epoch 0
  k_wfcb<<<2048, 256, 0, stream>>>(Wfc, Wfcb);
  // encoder layer0 ih-part: P0 = gather(emb, x) @ Wih0^T + bih0
  k_gemm<1><<<512, 256, 0, stream>>>(nullptr, x, emb, Wih, bih, P0);
  // layer0 scan (stores H0 in-place into P0); final h0 -> h0buf slot 0
  k_scan<<<256, 256, 0, stream>>>(P0, Whh, bhh, h0buf, flags, 1, 0u);
  // layer1 ih-part: P1 = H0 @ Wih1^T + bih1
  k_gemm<0><<<512, 256, 0, stream>>>(P0, nullptr, nullptr, Wih + 262144, bih + 512, P1);
  // layer1 scan; final h1 -> h1buf slot 0
  k_scan<<<256, 256, 0, stream>>>(P1, Whh + 262144, bhh + 512, h1buf, flags, 0, 256u);
  // decoder: 32 greedy steps + h_fin epilogue
  k_decoder<<<256, 256, 0, stream>>>(emb, Wih, Whh, bih, bhh, Wfc, bfc, Wfcb, h0buf, h1buf,
                                     h1bf, pmaxp, best, flags, out, 512u);
}

// Round 2
// 7705.996 us; speedup vs baseline: 3.0038x; 3.0038x over previous
//
#include <hip/hip_runtime.h>
#include <hip/hip_bf16.h>

// trajectory2seq: 2-layer Elman RNN encoder (SEQ=256) + greedy decoder (32 steps)
//  - encoder ih-parts hoisted into two big fp32 GEMMs (k_gemm)
//  - persistent scan kernels for the hh-recurrence (weights in VGPRs, flag barriers)
//  - decoder: one persistent kernel; cell in fp32 (LDS weights), logits via bf16 MFMA
//    + exact-fp32 argmax refinement (margin 0.05)
// R2: ALL intra-kernel cross-wg traffic via device-scope RELAXED atomics (sc-flagged,
// coherent at IF$) — no acquire/release fences anywhere (R1's per-poll buffer_inv/wbl2
// was 32us/barrier). Races fixed: best[] reset by wg250 between full barriers; last
// decoder barrier widened to full grid before h_fin epilogue.

typedef float v4f __attribute__((ext_vector_type(4)));
typedef short short8 __attribute__((ext_vector_type(8)));
typedef unsigned long long u64;

#define HID 512
#define NBAT 64
#define SEQL 256
#define NV 32000
#define TDEC 32
#define BH (64 * 512)
#define FPAD 16  // flags padded to 64B lines

__device__ __forceinline__ unsigned short f2bf(float f) {
  unsigned u = __float_as_uint(f);
  u = u + 0x7FFFu + ((u >> 16) & 1u);  // RNE
  return (unsigned short)(u >> 16);
}
__device__ __forceinline__ unsigned fenc(float f) {
  unsigned u = __float_as_uint(f);
  return (u & 0x80000000u) ? ~u : (u | 0x80000000u);
}
// device-scope relaxed atomics (coherent, no cache-maintenance ops)
__device__ __forceinline__ float ldf(const float* p) {
  return __hip_atomic_load(p, __ATOMIC_RELAXED, __HIP_MEMORY_SCOPE_AGENT);
}
__device__ __forceinline__ void stf(float* p, float v) {
  __hip_atomic_store(p, v, __ATOMIC_RELAXED, __HIP_MEMORY_SCOPE_AGENT);
}
__device__ __forceinline__ u64 ld8(const void* p) {
  return __hip_atomic_load((const u64*)p, __ATOMIC_RELAXED, __HIP_MEMORY_SCOPE_AGENT);
}

// fence-free flag barrier: drain own stores, publish epoch, poll relaxed.
__device__ __forceinline__ void wgbar(int* flags, int wg, int first, int count, unsigned ep) {
  __atomic_signal_fence(__ATOMIC_SEQ_CST);
  __builtin_amdgcn_s_waitcnt(0);  // per-wave: sc-stores reached the coherent point
  __syncthreads();
  if (threadIdx.x == 0)
    __hip_atomic_store(&flags[wg * FPAD], (int)ep, __ATOMIC_RELAXED, __HIP_MEMORY_SCOPE_AGENT);
  if ((int)threadIdx.x < 64) {
    for (int f = first + (int)threadIdx.x; f < first + count; f += 64) {
      while ((unsigned)__hip_atomic_load(&flags[f * FPAD], __ATOMIC_RELAXED,
                                         __HIP_MEMORY_SCOPE_AGENT) < ep)
        __builtin_amdgcn_s_sleep(2);
    }
  }
  __atomic_signal_fence(__ATOMIC_SEQ_CST);
  __syncthreads();
}

// ---------------- W_fc fp32 -> bf16 ----------------
__global__ void k_wfcb(const float* __restrict__ W, unsigned short* __restrict__ Wb) {
  const int n = NV * HID;
  for (int i = ((int)blockIdx.x * 256 + (int)threadIdx.x) * 8; i < n; i += 2048 * 256 * 8) {
    v4f a = *(const v4f*)(W + i);
    v4f b = *(const v4f*)(W + i + 4);
    short8 o;
    o[0] = (short)f2bf(a[0]); o[1] = (short)f2bf(a[1]);
    o[2] = (short)f2bf(a[2]); o[3] = (short)f2bf(a[3]);
    o[4] = (short)f2bf(b[0]); o[5] = (short)f2bf(b[1]);
    o[6] = (short)f2bf(b[2]); o[7] = (short)f2bf(b[3]);
    *(short8*)(Wb + i) = o;
  }
}

// ---------------- fp32 GEMM: P[i][j] = sum_k A[i][k]*W[j][k] + bias[j] ----------------
template <int GATHER>
__global__ __launch_bounds__(256, 2) void k_gemm(const float* __restrict__ A,
                                                 const int* __restrict__ xtok,
                                                 const float* __restrict__ emb,
                                                 const float* __restrict__ W,
                                                 const float* __restrict__ bias,
                                                 float* __restrict__ P) {
  __shared__ __align__(16) float As[32 * 132];
  __shared__ __align__(16) float Bs[32 * 132];
  const int tid = threadIdx.x;
  const int i0 = ((int)blockIdx.x >> 2) * 128, j0 = ((int)blockIdx.x & 3) * 128;
  const int tx = tid & 15, ty = tid >> 4;
  float acc[8][8] = {};
  const int sa = 4 * ((tx >> 2) & 1);
  const int sb = 4 * ((ty >> 2) & 1);
  const int pa0 = (tx * 8) ^ sa, pa1 = (tx * 8 + 4) ^ sa;
  const int pb0 = (ty * 8) ^ sb, pb1 = (ty * 8 + 4) ^ sb;
  for (int kc = 0; kc < HID; kc += 32) {
#pragma unroll
    for (int u = 0; u < 4; u++) {
      int lin = tid + u * 256;
      int il = lin >> 3, kq = (lin & 7) * 4;
      int pi = il ^ (4 * ((il >> 5) & 1));
      const float* asrc;
      if (GATHER) {
        int row = i0 + il;
        int tok = xtok[(row & 63) * SEQL + (row >> 6)];  // x[b][t], row = t*64+b
        asrc = emb + (size_t)tok * HID + kc + kq;
      } else {
        asrc = A + (size_t)(i0 + il) * HID + kc + kq;
      }
      v4f av = *(const v4f*)asrc;
      v4f bv = *(const v4f*)(W + (size_t)(j0 + il) * HID + kc + kq);
      As[(kq + 0) * 132 + pi] = av[0]; As[(kq + 1) * 132 + pi] = av[1];
      As[(kq + 2) * 132 + pi] = av[2]; As[(kq + 3) * 132 + pi] = av[3];
      Bs[(kq + 0) * 132 + pi] = bv[0]; Bs[(kq + 1) * 132 + pi] = bv[1];
      Bs[(kq + 2) * 132 + pi] = bv[2]; Bs[(kq + 3) * 132 + pi] = bv[3];
    }
    __syncthreads();
#pragma unroll 8
    for (int k = 0; k < 32; k++) {
      v4f a0 = *(const v4f*)&As[k * 132 + pa0];
      v4f a1 = *(const v4f*)&As[k * 132 + pa1];
      v4f b0 = *(const v4f*)&Bs[k * 132 + pb0];
      v4f b1 = *(const v4f*)&Bs[k * 132 + pb1];
      float ar[8] = {a0[0], a0[1], a0[2], a0[3], a1[0], a1[1], a1[2], a1[3]};
      float br[8] = {b0[0], b0[1], b0[2], b0[3], b1[0], b1[1], b1[2], b1[3]};
#pragma unroll
      for (int r = 0; r < 8; r++)
#pragma unroll
        for (int c = 0; c < 8; c++) acc[r][c] = fmaf(ar[r], br[c], acc[r][c]);
    }
    __syncthreads();
  }
  v4f bl0 = *(const v4f*)(bias + j0 + ty * 8);
  v4f bl1 = *(const v4f*)(bias + j0 + ty * 8 + 4);
#pragma unroll
  for (int r = 0; r < 8; r++) {
    float* dst = P + (size_t)(i0 + tx * 8 + r) * HID + j0 + ty * 8;
    v4f o0 = {acc[r][0] + bl0[0], acc[r][1] + bl0[1], acc[r][2] + bl0[2], acc[r][3] + bl0[3]};
    v4f o1 = {acc[r][4] + bl1[0], acc[r][5] + bl1[1], acc[r][6] + bl1[2], acc[r][7] + bl1[3]};
    *(v4f*)dst = o0;
    *(v4f*)(dst + 4) = o1;
  }
}

// ---------------- persistent recurrence scan ----------------
// 256 wgs = 8 batch-groups (8 batches) x 32 j-groups (16 neurons); Whh slice in VGPRs.
__global__ __launch_bounds__(256, 2) void k_scan(float* __restrict__ P,
                                                 const float* __restrict__ Whh,
                                                 const float* __restrict__ bhh,
                                                 float* __restrict__ hbuf,
                                                 int* __restrict__ flags, int store_h,
                                                 unsigned ep) {
  __shared__ __align__(16) float hs[32 * 132];
  const int wg = blockIdx.x, tid = threadIdx.x;
  const int bg = wg >> 5, jg = wg & 31;
  const int b0 = bg * 8, j0 = jg * 16;
  const int bh = tid & 1, jg2 = (tid >> 1) & 3, ks = tid >> 3;
  v4f wv[4][4];
#pragma unroll
  for (int jj = 0; jj < 4; jj++)
#pragma unroll
    for (int i4 = 0; i4 < 4; i4++)
      wv[jj][i4] = *(const v4f*)(Whh + (size_t)(j0 + jg2 * 4 + jj) * HID + ks * 16 + i4 * 4);
  for (int t = 0; t < SEQL; t++) {
    const int p = t & 1;
    float* Pt = P + (size_t)t * BH;
    const float* hsrc = hbuf + p * BH + b0 * HID;
#pragma unroll
    for (int u = 0; u < 16; u++) {
      int lin = tid + u * 256;
      int b = lin >> 9, k = lin & 511;
      hs[(k >> 4) * 132 + b * 16 + (k & 15)] = ldf(hsrc + b * HID + k);
    }
    __syncthreads();
    float acc[4][4] = {};
#pragma unroll
    for (int i4 = 0; i4 < 4; i4++) {
#pragma unroll
      for (int bb = 0; bb < 4; bb++) {
        int b = bh * 4 + bb;
        v4f hv = *(const v4f*)&hs[ks * 132 + b * 16 + i4 * 4];
#pragma unroll
        for (int jj = 0; jj < 4; jj++) {
          float a = acc[bb][jj];
          a = fmaf(hv[0], wv[jj][i4][0], a);
          a = fmaf(hv[1], wv[jj][i4][1], a);
          a = fmaf(hv[2], wv[jj][i4][2], a);
          a = fmaf(hv[3], wv[jj][i4][3], a);
          acc[bb][jj] = a;
        }
      }
    }
    __syncthreads();  // reuse hs as partials [ks32][b8][j16]
#pragma unroll
    for (int bb = 0; bb < 4; bb++) {
      v4f pv = {acc[bb][0], acc[bb][1], acc[bb][2], acc[bb][3]};
      *(v4f*)&hs[ks * 132 + (bh * 4 + bb) * 16 + jg2 * 4] = pv;
    }
    __syncthreads();
    if (tid < 128) {
      int bb = tid >> 4, jj = tid & 15;
      float sum = 0.f;
#pragma unroll
      for (int k2 = 0; k2 < 32; k2++) sum += hs[k2 * 132 + bb * 16 + jj];
      int jglob = j0 + jj, bglob = b0 + bb;
      float z = Pt[bglob * HID + jglob] + bhh[jglob] + sum;
      float h = tanhf(z);
      stf(&hbuf[(p ^ 1) * BH + bglob * HID + jglob], h);
      if (store_h) Pt[bglob * HID + jglob] = h;  // H history for layer-1 GEMM (next kernel)
    }
    wgbar(flags, wg, bg * 32, 32, ++ep);
  }
}

// ---------------- persistent decoder ----------------
__global__ __launch_bounds__(256, 1) void k_decoder(
    const float* __restrict__ emb, const float* __restrict__ Wih, const float* __restrict__ Whh,
    const float* __restrict__ bih, const float* __restrict__ bhh, const float* __restrict__ Wfc,
    const float* __restrict__ bfc, const unsigned short* __restrict__ Wfcb,
    float* __restrict__ h0buf, float* __restrict__ h1buf, unsigned short* __restrict__ h1bf,
    float* __restrict__ pmaxp, unsigned long long* __restrict__ best, int* __restrict__ flags,
    float* __restrict__ out, unsigned ep) {
  __shared__ __align__(16) float Wl[4 * 4224];  // [ih0,hh0,ih1,hh1][ks32][j8][k16]+pad
  __shared__ __align__(16) float es[32 * 268];  // stage / partials / pmr / red
  __shared__ __align__(16) float hss[32 * 268]; // stage / E: h-row cache
  const int wg = blockIdx.x, tid = threadIdx.x;
  const int bg = wg >> 6, jgD = wg & 63;
  const int bh = tid & 3, jg2 = (tid >> 2) & 1, ks = tid >> 3;
  for (int m = 0; m < 4; m++) {
    const float* src = ((m & 1) ? Whh : Wih) + (size_t)(m >> 1) * HID * HID;
#pragma unroll
    for (int u = 0; u < 4; u++) {
      int lin = tid + u * 256;
      int j = lin >> 7, k4 = (lin & 127) * 4;
      v4f v = *(const v4f*)(src + (size_t)(jgD * 8 + j) * HID + k4);
      *(v4f*)&Wl[m * 4224 + (k4 >> 4) * 132 + j * 16 + (k4 & 15)] = v;
    }
  }
  for (int st = 0; st < TDEC; st++) {
    const int p = st & 1;
    // ---- phases A (l0) / B (l1) ----
    for (int ph = 0; ph < 2; ph++) {
      if (ph == 0) {
        // es <- emb[tok] (plain input, vectorized); hss <- h0 slot p (atomic)
#pragma unroll
        for (int u = 0; u < 8; u++) {
          int lin = tid + u * 256;
          int b = lin >> 7, k4 = (lin & 127) * 4;
          unsigned vtok = 0u;
          if (st > 0) {
            u64 kk = ld8(&best[bg * 16 + b]);
            vtok = 0xFFFFFFFFu - (unsigned)(kk & 0xFFFFFFFFull);
            if (vtok >= (unsigned)NV) vtok = 0u;
          }
          v4f av = *(const v4f*)(emb + (size_t)vtok * HID + k4);
          *(v4f*)&es[(k4 >> 4) * 268 + b * 16 + (k4 & 15)] = av;
        }
#pragma unroll
        for (int u = 0; u < 32; u++) {
          int lin = tid + u * 256;
          int b = lin >> 9, k = lin & 511;
          hss[(k >> 4) * 268 + b * 16 + (k & 15)] = ldf(h0buf + p * BH + (bg * 16 + b) * HID + k);
        }
      } else {
#pragma unroll
        for (int u = 0; u < 32; u++) {
          int lin = tid + u * 256;
          int b = lin >> 9, k = lin & 511;
          int off = (k >> 4) * 268 + b * 16 + (k & 15);
          int row = (bg * 16 + b) * HID + k;
          es[off] = ldf(h0buf + (p ^ 1) * BH + row);
          hss[off] = ldf(h1buf + p * BH + row);
        }
      }
      __syncthreads();
      float acc[4][4] = {};
      const float* Wi = &Wl[(ph * 2 + 0) * 4224];
      const float* Wh = &Wl[(ph * 2 + 1) * 4224];
#pragma unroll
      for (int i4 = 0; i4 < 4; i4++) {
        v4f wi[4], wh[4];
#pragma unroll
        for (int jj = 0; jj < 4; jj++) {
          wi[jj] = *(const v4f*)&Wi[ks * 132 + (jg2 * 4 + jj) * 16 + i4 * 4];
          wh[jj] = *(const v4f*)&Wh[ks * 132 + (jg2 * 4 + jj) * 16 + i4 * 4];
        }
#pragma unroll
        for (int bb = 0; bb < 4; bb++) {
          int b = bh * 4 + bb;
          v4f evv = *(const v4f*)&es[ks * 268 + b * 16 + i4 * 4];
          v4f hvv = *(const v4f*)&hss[ks * 268 + b * 16 + i4 * 4];
#pragma unroll
          for (int jj = 0; jj < 4; jj++) {
            float a = acc[bb][jj];
            a = fmaf(evv[0], wi[jj][0], a); a = fmaf(evv[1], wi[jj][1], a);
            a = fmaf(evv[2], wi[jj][2], a); a = fmaf(evv[3], wi[jj][3], a);
            a = fmaf(hvv[0], wh[jj][0], a); a = fmaf(hvv[1], wh[jj][1], a);
            a = fmaf(hvv[2], wh[jj][2], a); a = fmaf(hvv[3], wh[jj][3], a);
            acc[bb][jj] = a;
          }
        }
      }
      __syncthreads();  // partials alias es: [ks32][b16][j8]
#pragma unroll
      for (int bb = 0; bb < 4; bb++) {
        v4f pv = {acc[bb][0], acc[bb][1], acc[bb][2], acc[bb][3]};
        *(v4f*)&es[ks * 132 + (bh * 4 + bb) * 8 + jg2 * 4] = pv;
      }
      __syncthreads();
      if (tid < 128) {
        int b = tid >> 3, j = tid & 7;
        float sum = 0.f;
#pragma unroll
        for (int k2 = 0; k2 < 32; k2++) sum += es[k2 * 132 + b * 8 + j];
        int jglob = jgD * 8 + j, bglob = bg * 16 + b;
        float z = bih[ph * HID + jglob] + bhh[ph * HID + jglob] + sum;
        float h = tanhf(z);
        float* hb = (ph ? h1buf : h0buf);
        stf(&hb[(p ^ 1) * BH + bglob * HID + jglob], h);
        if (ph) {  // pack bf16 pairs, even-j lanes store 4B
          unsigned hbv = f2bf(h);
          unsigned nb = (unsigned)__shfl_down((int)hbv, 1);
          if ((j & 1) == 0)
            __hip_atomic_store((unsigned*)(h1bf + (size_t)bglob * HID + jglob),
                               hbv | (nb << 16), __ATOMIC_RELAXED, __HIP_MEMORY_SCOPE_AGENT);
        }
      }
      if (ph == 0) wgbar(flags, wg, bg * 64, 64, ++ep);
      else         wgbar(flags, wg, 0, 256, ++ep);
    }
    // ---- phase C: logits = h1 @ Wfc^T + bfc (bf16 MFMA); wg250 resets best ----
    if (wg < 250) {
      const int w = tid >> 6, lane = tid & 63;
      const int l16 = lane & 15, quad = lane >> 4;
      const int n0 = wg * 128 + w * 32;
      const int nc0 = n0 + l16, nc1 = n0 + 16 + l16;
      const float bf0 = bfc[nc0], bf1 = bfc[nc1];
      const int ko = quad * 8;
      v4f acc[4][2] = {};
#pragma unroll 4
      for (int kc = 0; kc < HID; kc += 32) {
        short8 b0 = *(const short8*)(Wfcb + (size_t)nc0 * HID + kc + ko);
        short8 b1 = *(const short8*)(Wfcb + (size_t)nc1 * HID + kc + ko);
#pragma unroll
        for (int mb = 0; mb < 4; mb++) {
          union { u64 q[2]; short8 s; } au;
          const unsigned short* hr = h1bf + (size_t)(mb * 16 + l16) * HID + kc + ko;
          au.q[0] = ld8(hr);
          au.q[1] = ld8(hr + 4);
          acc[mb][0] = __builtin_amdgcn_mfma_f32_16x16x32_bf16(au.s, b0, acc[mb][0], 0, 0, 0);
          acc[mb][1] = __builtin_amdgcn_mfma_f32_16x16x32_bf16(au.s, b1, acc[mb][1], 0, 0, 0);
        }
      }
      float* pmr = es;  // [4 waves][64 rows]
#pragma unroll
      for (int mb = 0; mb < 4; mb++) {
#pragma unroll
        for (int r = 0; r < 4; r++) {
          float v0 = acc[mb][0][r] + bf0;
          float v1 = acc[mb][1][r] + bf1;
          int m = mb * 16 + quad * 4 + r;  // C/D: col=lane&15, row=quad*4+reg
          stf(&out[(size_t)(m * TDEC + st) * NV + nc0], v0);
          stf(&out[(size_t)(m * TDEC + st) * NV + nc1], v1);
          float mx = fmaxf(v0, v1);
          mx = fmaxf(mx, __shfl_xor(mx, 1));
          mx = fmaxf(mx, __shfl_xor(mx, 2));
          mx = fmaxf(mx, __shfl_xor(mx, 4));
          mx = fmaxf(mx, __shfl_xor(mx, 8));
          if (l16 == 0) pmr[w * 64 + m] = mx;
        }
      }
      __syncthreads();
      if (tid < 64) {
        float m4 = fmaxf(fmaxf(pmr[tid], pmr[64 + tid]), fmaxf(pmr[128 + tid], pmr[192 + tid]));
        stf(&pmaxp[wg * 64 + tid], m4);
      }
    } else if (wg == 250 && tid < 64) {
      // safe window: after B's full barrier (all A reads of best done), before E's atomicMax
      __hip_atomic_store(&best[tid], 0ull, __ATOMIC_RELAXED, __HIP_MEMORY_SCOPE_AGENT);
    }
    wgbar(flags, wg, 0, 256, ++ep);
    // ---- phase E: candidate refine + argmax; wg = b*4 + quarter ----
    {
      const int b = wg >> 2, q = wg & 3;
      const float* hrow = h1buf + (p ^ 1) * BH + b * HID;
      hss[tid] = ldf(hrow + tid);
      hss[tid + 256] = ldf(hrow + tid + 256);
      float* red = es;
      red[tid] = (tid < 250) ? ldf(&pmaxp[tid * 64 + b]) : -3.0e38f;
      __syncthreads();
      for (int o = 128; o > 0; o >>= 1) {
        if (tid < o) red[tid] = fmaxf(red[tid], red[tid + o]);
        __syncthreads();
      }
      const float thr = red[0] - 0.05f;
      const size_t ob = (size_t)(b * TDEC + st) * NV + q * 8000;
      for (int i = tid * 2; i < 8000; i += 512) {
        u64 qq = ld8(out + ob + i);
        float lv[2] = {__uint_as_float((unsigned)qq), __uint_as_float((unsigned)(qq >> 32))};
#pragma unroll
        for (int c = 0; c < 2; c++) {
          if (lv[c] >= thr) {
            int vidx = q * 8000 + i + c;
            const v4f* h4 = (const v4f*)hss;
            const v4f* w4 = (const v4f*)(Wfc + (size_t)vidx * HID);
            v4f s0 = 0, s1 = 0;
            for (int k = 0; k < 128; k += 2) {
              s0 += h4[k] * w4[k];
              s1 += h4[k + 1] * w4[k + 1];
            }
            v4f sv = s0 + s1;
            float d = bfc[vidx] + sv[0] + sv[1] + sv[2] + sv[3];
            u64 key = ((u64)fenc(d) << 32) | (u64)(0xFFFFFFFFu - (unsigned)vidx);
            atomicMax(&best[b], key);
          }
        }
      }
    }
    // last step: full-grid barrier so the h_fin epilogue sees every group's final h
    if (st == TDEC - 1) wgbar(flags, wg, 0, 256, ++ep);
    else                wgbar(flags, wg, bg * 64, 64, ++ep);
  }
  // h_fin: [2][64][512] appended after logits (final h lives in slot 0)
  int lin = wg * 256 + tid;
  int l = lin >> 15, r2 = lin & 32767;
  out[65536000 + lin] = ldf(&(l ? h1buf : h0buf)[r2]);
}

extern "C" void kernel_launch(void* const* d_in, const int* in_sizes, int n_in, void* d_out,
                              int out_size, void* d_ws, size_t ws_size, hipStream_t stream) {
  const int* x = (const int*)d_in[0];
  const float* emb = (const float*)d_in[1];
  const float* Wih = (const float*)d_in[2];
  const float* Whh = (const float*)d_in[3];
  const float* bih = (const float*)d_in[4];
  const float* bhh = (const float*)d_in[5];
  const float* Wfc = (const float*)d_in[6];
  const float* bfc = (const float*)d_in[7];
  float* out = (float*)d_out;
  char* ws = (char*)d_ws;

  float* P0 = (float*)ws;                          // [256][64][512] -> becomes H0 in-place
  float* P1 = P0 + (size_t)SEQL * BH;              // [256][64][512]
  unsigned short* Wfcb = (unsigned short*)(P1 + (size_t)SEQL * BH);  // [32000][512] bf16
  char* small = (char*)(Wfcb + (size_t)NV * HID);
  float* h0buf = (float*)small;                    // [2][64][512]
  float* h1buf = h0buf + 2 * BH;                   // [2][64][512]
  unsigned short* h1bf = (unsigned short*)(h1buf + 2 * BH);  // [64][512] bf16
  float* pmaxp = (float*)(h1bf + BH);              // [250+pad][64]
  unsigned long long* best = (unsigned long long*)(pmaxp + 256 * 64);  // [64]
  int* flags = (int*)(best + 64);                  // [256*FPAD]
  size_t small_bytes = (size_t)2 * BH * 4 + (size_t)2 * BH * 4 + BH * 2 + 256 * 64 * 4 +
                       64 * 8 + 256 * FPAD * 4;

  hipMemsetAsync(small, 0, small_bytes, stream);  // h=0, best=0, flags epoch 0
  k_wfcb<<<2048, 256, 0, stream>>>(Wfc, Wfcb);
  // encoder layer0 ih-part: P0 = gather(emb, x) @ Wih0^T + bih0
  k_gemm<1><<<512, 256, 0, stream>>>(nullptr, x, emb, Wih, bih, P0);
  // layer0 scan (stores H0 in-place into P0); final h0 -> h0buf slot 0
  k_scan<<<256, 256, 0, stream>>>(P0, Whh, bhh, h0buf, flags, 1, 0u);
  // layer1 ih-part: P1 = H0 @ Wih1^T + bih1
  k_gemm<0><<<512, 256, 0, stream>>>(P0, nullptr, nullptr, Wih + 262144, bih + 512, P1);
  // layer1 scan; final h1 -> h1buf slot 0
  k_scan<<<256, 256, 0, stream>>>(P1, Whh + 262144, bhh + 512, h1buf, flags, 0, 256u);
  // decoder: 32 greedy steps (eps 513..513+33*4) + h_fin epilogue
  k_decoder<<<256, 256, 0, stream>>>(emb, Wih, Whh, bih, bhh, Wfc, bfc, Wfcb, h0buf, h1buf,
                                     h1bf, pmaxp, best, flags, out, 512u);
}